// Round 2
// baseline (11358.932 us; speedup 1.0000x reference)
//
#include <hip/hip_runtime.h>
#include <stdint.h>
#include <stddef.h>

// Problem dims (fixed): B=32 TENC=2048 LIS=512 HID=512 EMB=256 CLS=64 KEY=128 VAL=128 T=64 steps
// Outputs (f32, concat): logits [64,32,64] @0 ; preds.T [32,64] @131072 ; atts [64,32,2048] @133120
// Structure: k_init + k_proj (normal launches) + ONE persistent kernel (256 blocks x 256 thr, 1/CU)
// using a SOFTWARE grid barrier (device-scope atomics; release-add / acquire-spin handles the
// per-XCD L2 non-coherence). No cooperative launch (graph-capture-safe).
//   per step i (1..63):  bar; G1 (gates1+act1 fused, +atts(i-1) out, +finalize(i-1));
//                        bar; G2 (gates2+act2 fused, +zero next-parity ctx accum);
//                        bar; ATT (query, energies, exp, Ssum/ctxnum partials)
// State double-buffered by step parity: h1,c1,h2,c2,ctxnum,Ssum.

struct P {
  const float* listener; const int* outlen; const int* ptgt;
  const float* embed;
  const float *W_ih1, *W_hh1, *b_ih1, *b_hh1;
  const float *W_ih2, *W_hh2, *b_ih2, *b_hh2;
  const float *W_s, *b_s, *W_h, *b_h, *W_v, *b_v, *W_c, *b_c;
  const float *h1_0, *c1_0, *h2_0, *c2_0;
  float* keyT;            // [32][128][2048]
  float* value;           // [32][2048][128]
  float* h1;              // [2][32][512] ping-pong by step parity
  float* c1;              // [2][32][512]
  float* h2;              // [2][32][512]
  float* c2;              // [2][32][512]
  float* wbuf;            // [32][2048] unnormalized att weights of the latest ATT
  float* ctxnum;          // [2][32][128]
  float* Ssum;            // [2][32]
  unsigned* bar;          // software grid-barrier counter (monotonic)
  float* out;
};

__device__ __forceinline__ float sigf(float x) { return 1.0f / (1.0f + expf(-x)); }

// exact jax threefry2x32 (20 rounds)
__device__ __forceinline__ void tf2x32(uint32_t k0, uint32_t k1,
                                       uint32_t x0, uint32_t x1,
                                       uint32_t& o0, uint32_t& o1) {
  uint32_t k2 = k0 ^ k1 ^ 0x1BD11BDAu;
#define TFR(r) { x0 += x1; x1 = (x1 << (r)) | (x1 >> (32 - (r))); x1 ^= x0; }
  x0 += k0; x1 += k1;
  TFR(13) TFR(15) TFR(26) TFR(6)   x0 += k1; x1 += k2 + 1u;
  TFR(17) TFR(29) TFR(16) TFR(24)  x0 += k2; x1 += k0 + 2u;
  TFR(13) TFR(15) TFR(26) TFR(6)   x0 += k0; x1 += k1 + 3u;
  TFR(17) TFR(29) TFR(16) TFR(24)  x0 += k1; x1 += k2 + 4u;
  TFR(13) TFR(15) TFR(26) TFR(6)   x0 += k2; x1 += k0 + 5u;
#undef TFR
  o0 = x0; o1 = x1;
}

__device__ __forceinline__ float gumbel_f(uint32_t bits) {
  float f = __uint_as_float((bits >> 9) | 0x3f800000u) - 1.0f;
  float u = (f == 0.0f) ? 1.17549435e-38f : f;
  return -logf(-logf(u));
}

// ---- software grid barrier: monotonic counter, release-arrive / acquire-spin ----
__device__ __forceinline__ void gbar(unsigned* cnt, unsigned target) {
  __syncthreads();
  if (threadIdx.x == 0) {
    // release: prior stores flushed to device-coherent point before the add lands
    __hip_atomic_fetch_add(cnt, 1u, __ATOMIC_RELEASE, __HIP_MEMORY_SCOPE_AGENT);
    // acquire: each poll invalidates stale L1/L2 so post-barrier reads are fresh
    while (__hip_atomic_load(cnt, __ATOMIC_ACQUIRE, __HIP_MEMORY_SCOPE_AGENT) < target) {
      __builtin_amdgcn_s_sleep(2);
    }
  }
  __syncthreads();
}

// ---------------- init: states (parity 0) + zero both ctx accumulators + barrier ----------------
__global__ void __launch_bounds__(256) k_init(P p) {
  int idx = blockIdx.x * 256 + threadIdx.x;   // grid 64*256 = 16384
  p.h1[idx] = p.h1_0[idx];
  p.c1[idx] = p.c1_0[idx];
  p.h2[idx] = p.h2_0[idx];
  p.c2[idx] = p.c2_0[idx];
  if (idx < 8192) p.ctxnum[idx] = 0.0f;
  if (idx < 64)   p.Ssum[idx]   = 0.0f;
  if (idx == 0)   *p.bar        = 0u;
}

// ---------------- hoisted projections: key_enc (f32, transposed) + value (f32) ----------------
__global__ void __launch_bounds__(256) k_proj(P p) {
  const int blk = blockIdx.x, tid = threadIdx.x;      // grid 4096
  const int b = blk >> 7, tb = blk & 127, t0 = tb * 16;
  __shared__ float lst[16 * 512];                     // 32 KB
  const float* src = p.listener + ((size_t)b * 2048 + t0) * 512;
  for (int n = 0; n < 32; ++n) {
    int idx = n * 256 + tid;
    lst[idx] = src[idx];
  }
  __syncthreads();
  const int c = tid; // 0..127 -> key col c ; 128..255 -> value col c-128
  const float* wr = (c < 128) ? (p.W_h + c * 512) : (p.W_v + (c - 128) * 512);
  const float bias = (c < 128) ? p.b_h[c] : p.b_v[c - 128];
  float acc[16];
#pragma unroll
  for (int r = 0; r < 16; ++r) acc[r] = 0.0f;
  for (int k4 = 0; k4 < 128; ++k4) {
    float4 w4 = ((const float4*)wr)[k4];
#pragma unroll
    for (int r = 0; r < 16; ++r) {
      float4 x4 = ((const float4*)(lst + r * 512))[k4];
      acc[r] = fmaf(w4.x, x4.x, fmaf(w4.y, x4.y, fmaf(w4.z, x4.z, fmaf(w4.w, x4.w, acc[r]))));
    }
  }
  if (c < 128) {
#pragma unroll
    for (int r = 0; r < 16; ++r)
      p.keyT[((size_t)b * 128 + c) * 2048 + t0 + r] = acc[r] + bias;
  } else {
#pragma unroll
    for (int r = 0; r < 16; ++r)
      p.value[((size_t)b * 2048 + t0 + r) * 128 + (c - 128)] = acc[r] + bias;
  }
}

// ---------------- finalize step `step` for batch b: logits + categorical sample ----------------
// executed by one full wave (tid = 0..63); c = tid
__device__ void do_finalize(const P& p, int step, int b, int tid) {
  const int c = tid;
  const int par = step & 1;
  const float* h2p  = p.h2 + par * 16384 + b * 512;
  const float* ctxp = p.ctxnum + par * 4096 + b * 128;
  const float invS = 1.0f / fmaxf(p.Ssum[par * 32 + b], 1e-12f);
  const float* wr = p.W_c + c * 640;
  float a0 = 0.f, a1 = 0.f, a2 = 0.f, a3 = 0.f;
#pragma unroll 8
  for (int k4 = 0; k4 < 128; ++k4) {
    float4 w4 = ((const float4*)wr)[k4];
    float4 x4 = ((const float4*)h2p)[k4];
    a0 = fmaf(w4.x, x4.x, a0); a1 = fmaf(w4.y, x4.y, a1);
    a2 = fmaf(w4.z, x4.z, a2); a3 = fmaf(w4.w, x4.w, a3);
  }
#pragma unroll
  for (int k4 = 0; k4 < 32; ++k4) {
    float4 w4 = ((const float4*)(wr + 512))[k4];
    float4 x4 = ((const float4*)ctxp)[k4];
    a0 = fmaf(w4.x, x4.x * invS, a0); a1 = fmaf(w4.y, x4.y * invS, a1);
    a2 = fmaf(w4.z, x4.z * invS, a2); a3 = fmaf(w4.w, x4.w * invS, a3);
  }
  float lg = p.b_c[c] + ((a0 + a1) + (a2 + a3));
  p.out[(size_t)(step * 32 + b) * 64 + c] = lg;
  uint32_t n0, n1, r0, r1;
  tf2x32(0u, 2u, 0u, (uint32_t)step, n0, n1);          // fold_in(key(2), step)
  tf2x32(n0, n1, 0u, (uint32_t)(b * 64 + c), r0, r1);  // partitionable bits at pos b*64+c
  float z = gumbel_f(r0 ^ r1) + lg;
  int ix = c;
  for (int off = 32; off; off >>= 1) {
    float zz = __shfl_xor(z, off, 64); int ii = __shfl_xor(ix, off, 64);
    if (zz > z || (zz == z && ii < ix)) { z = zz; ix = ii; }
  }
  if (c == 0) p.out[131072 + b * 64 + step] = (float)ix;
}

// ---------------- phase G1: gates1 + act1 fused; + atts(i-1) out + finalize(i-1) ----------------
// 256 blocks; block owns j0=blk*2 -> rows {j,j+512,j+1024,j+1536}, one K=896 dot per thread
__device__ void phase_g1(const P& p, int i, float* smem, int* smi, int blk, int tid) {
  const int par = i & 1, q1 = par ^ 1;
  float* sx   = smem;          // 32*132 = 4224
  float* sg   = smem + 4224;   // 256
  float* sinv = smem + 4480;   // 32
  // atts output for step i-1 (1 element/thread, 65536 total)
  {
    int flat = blk * 256 + tid;
    int b = flat >> 11, t = flat & 2047;
    float s = fmaxf(p.Ssum[q1 * 32 + b], 1e-12f);
    p.out[133120 + (size_t)((i - 1) * 32 + b) * 2048 + t] = p.wbuf[b * 2048 + t] / s;
  }
  if (tid < 32) {
    sinv[tid] = 1.0f / fmaxf(p.Ssum[q1 * 32 + tid], 1e-12f);
    smi[tid]  = p.ptgt[tid * 65 + (i - 1)];   // teacher forcing == 1 always
  }
  const int m = tid >> 5, b = tid & 31;
  const int j0 = blk * 2;
  const int row = j0 + (m & 1) + (m >> 1) * 512;
  const float* h1r  = p.h1 + q1 * 16384;
  const float* ctxr = p.ctxnum + q1 * 4096;
  float a0 = 0.f, a1 = 0.f, a2 = 0.f, a3 = 0.f;
  for (int kt = 0; kt < 7; ++kt) {   // K = 896 = 2*128 emb + 128 ctx + 4*128 h1
    __syncthreads();
    for (int n = 0; n < 16; ++n) {
      int idx = n * 256 + tid, fb = idx >> 7, kk = idx & 127;
      float v;
      if (kt < 2)       v = p.embed[smi[fb] * 256 + kt * 128 + kk];
      else if (kt == 2) v = ctxr[fb * 128 + kk] * sinv[fb];
      else              v = h1r[fb * 512 + (kt - 3) * 128 + kk];
      sx[fb * 132 + kk] = v;
    }
    __syncthreads();
    const float* wr = (kt < 3) ? (p.W_ih1 + row * 384 + kt * 128)
                               : (p.W_hh1 + row * 512 + (kt - 3) * 128);
    const float4* x4p = (const float4*)(sx + b * 132);
#pragma unroll
    for (int k4 = 0; k4 < 32; ++k4) {
      float4 w4 = ((const float4*)wr)[k4];
      float4 x4 = x4p[k4];
      a0 = fmaf(w4.x, x4.x, a0); a1 = fmaf(w4.y, x4.y, a1);
      a2 = fmaf(w4.z, x4.z, a2); a3 = fmaf(w4.w, x4.w, a3);
    }
  }
  sg[m * 32 + b] = ((a0 + a1) + (a2 + a3)) + p.b_ih1[row] + p.b_hh1[row];
  __syncthreads();
  if (tid < 64) {
    int jl = tid >> 5, bb = tid & 31, j = j0 + jl;
    float gi = sg[(0 + jl) * 32 + bb];
    float gf = sg[(2 + jl) * 32 + bb];
    float gg = sg[(4 + jl) * 32 + bb];
    float go = sg[(6 + jl) * 32 + bb];
    float cp = p.c1[q1 * 16384 + bb * 512 + j];
    float c  = sigf(gf) * cp + sigf(gi) * tanhf(gg);
    p.h1[par * 16384 + bb * 512 + j] = sigf(go) * tanhf(c);
    p.c1[par * 16384 + bb * 512 + j] = c;
  }
  if (blk < 32 && tid < 64) do_finalize(p, i - 1, blk, tid);
}

// ---------------- phase G2: gates2 + act2 fused; + zero next-parity accumulators ----------------
__device__ void phase_g2(const P& p, int i, float* smem, int blk, int tid) {
  const int par = i & 1, q1 = par ^ 1;
  float* sx = smem;
  float* sg = smem + 4224;
  // zero ctx accumulators of parity q1 = (i+1)&1 for ATT(i+1) (dead now: G1(i)/finalize(i-1) done)
  if (blk < 16) p.ctxnum[q1 * 4096 + blk * 256 + tid] = 0.0f;
  if (blk == 16 && tid < 32) p.Ssum[q1 * 32 + tid] = 0.0f;
  const int m = tid >> 5, b = tid & 31;
  const int j0 = blk * 2;
  const int row = j0 + (m & 1) + (m >> 1) * 512;
  const float* h1r = p.h1 + par * 16384;
  const float* h2r = p.h2 + q1 * 16384;
  float a0 = 0.f, a1 = 0.f, a2 = 0.f, a3 = 0.f;
  for (int kt = 0; kt < 8; ++kt) {   // K = 1024 = 4*128 h1 + 4*128 h2prev
    __syncthreads();
    for (int n = 0; n < 16; ++n) {
      int idx = n * 256 + tid, fb = idx >> 7, kk = idx & 127;
      float v = (kt < 4) ? h1r[fb * 512 + kt * 128 + kk]
                         : h2r[fb * 512 + (kt - 4) * 128 + kk];
      sx[fb * 132 + kk] = v;
    }
    __syncthreads();
    const float* wr = (kt < 4) ? (p.W_ih2 + row * 512 + kt * 128)
                               : (p.W_hh2 + row * 512 + (kt - 4) * 128);
    const float4* x4p = (const float4*)(sx + b * 132);
#pragma unroll
    for (int k4 = 0; k4 < 32; ++k4) {
      float4 w4 = ((const float4*)wr)[k4];
      float4 x4 = x4p[k4];
      a0 = fmaf(w4.x, x4.x, a0); a1 = fmaf(w4.y, x4.y, a1);
      a2 = fmaf(w4.z, x4.z, a2); a3 = fmaf(w4.w, x4.w, a3);
    }
  }
  sg[m * 32 + b] = ((a0 + a1) + (a2 + a3)) + p.b_ih2[row] + p.b_hh2[row];
  __syncthreads();
  if (tid < 64) {
    int jl = tid >> 5, bb = tid & 31, j = j0 + jl;
    float gi = sg[(0 + jl) * 32 + bb];
    float gf = sg[(2 + jl) * 32 + bb];
    float gg = sg[(4 + jl) * 32 + bb];
    float go = sg[(6 + jl) * 32 + bb];
    float cp = p.c2[q1 * 16384 + bb * 512 + j];
    float c  = sigf(gf) * cp + sigf(gi) * tanhf(gg);
    p.h2[par * 16384 + bb * 512 + j] = sigf(go) * tanhf(c);
    p.c2[par * 16384 + bb * 512 + j] = c;
  }
}

// ---------------- phase ATT: query, energies, exp*mask, Ssum & ctxnum partials ----------------
// 256 blocks = 32 b x 8 chunks of 256 t
__device__ void phase_att(const P& p, int i, float* smem, int blk, int tid) {
  const int par = i & 1;
  const int b = blk >> 3, ch = blk & 7, t0 = ch * 256;
  float* sh2  = smem;           // 512
  float* sq   = smem + 512;     // 128
  float* sw   = smem + 640;     // 256
  float* sred = smem + 896;     // 256
  float* sctx = smem + 1152;    // 256
  const float* h2p = p.h2 + par * 16384 + b * 512;
  sh2[tid] = h2p[tid];
  sh2[tid + 256] = h2p[tid + 256];
  __syncthreads();
  if (tid < 128) {  // query = W_s*h2 + b_s (redundant across the 8 chunks, cheap)
    const float* wr = p.W_s + tid * 512;
    float a0 = 0.f, a1 = 0.f, a2 = 0.f, a3 = 0.f;
    for (int j4 = 0; j4 < 128; ++j4) {
      float4 w4 = ((const float4*)wr)[j4];
      float4 h4 = ((const float4*)sh2)[j4];
      a0 = fmaf(w4.x, h4.x, a0); a1 = fmaf(w4.y, h4.y, a1);
      a2 = fmaf(w4.z, h4.z, a2); a3 = fmaf(w4.w, h4.w, a3);
    }
    sq[tid] = p.b_s[tid] + ((a0 + a1) + (a2 + a3));
  }
  __syncthreads();
  const int t = t0 + tid;
  const float* kc = p.keyT + (size_t)b * 262144 + t;
  float e0 = 0.f, e1 = 0.f, e2 = 0.f, e3 = 0.f;
#pragma unroll 4
  for (int k = 0; k < 128; k += 4) {
    e0 = fmaf(kc[(k + 0) * 2048], sq[k + 0], e0);
    e1 = fmaf(kc[(k + 1) * 2048], sq[k + 1], e1);
    e2 = fmaf(kc[(k + 2) * 2048], sq[k + 2], e2);
    e3 = fmaf(kc[(k + 3) * 2048], sq[k + 3], e3);
  }
  float e = (e0 + e1) + (e2 + e3);
  const int len = p.outlen[b];
  bool msk = (b == 0) || (t < len);
  float wv = msk ? expf(e) : 0.0f;
  p.wbuf[b * 2048 + t] = wv;
  sw[tid] = wv;
  sred[tid] = wv;
  __syncthreads();
  for (int s = 128; s > 0; s >>= 1) {
    if (tid < s) sred[tid] += sred[tid + s];
    __syncthreads();
  }
  if (tid == 0) atomicAdd(&p.Ssum[par * 32 + b], sred[0]);
  // context partial: sum over this chunk's 256 t
  {
    int v = tid & 127, half = tid >> 7;
    const float* vb = p.value + ((size_t)(b * 2048 + t0 + half * 128)) * 128 + v;
    float c0 = 0.f, c1v = 0.f;
#pragma unroll 4
    for (int tt = 0; tt < 128; tt += 2) {
      c0  = fmaf(sw[half * 128 + tt],     vb[(size_t)tt * 128],       c0);
      c1v = fmaf(sw[half * 128 + tt + 1], vb[(size_t)(tt + 1) * 128], c1v);
    }
    sctx[half * 128 + v] = c0 + c1v;
  }
  __syncthreads();
  if (tid < 128) atomicAdd(&p.ctxnum[par * 4096 + b * 128 + tid], sctx[tid] + sctx[128 + tid]);
}

// ---------------- the persistent decode loop (normal launch + software grid barrier) ----------------
__global__ void __launch_bounds__(256) k_loop(P p) {
  __shared__ float smem[4608];
  __shared__ int   smi[32];
  const int blk = blockIdx.x, tid = threadIdx.x;
  unsigned nb = 0;
  phase_att(p, 0, smem, blk, tid);
  for (int i = 1; i < 64; ++i) {
    gbar(p.bar, (++nb) * 256u);
    phase_g1(p, i, smem, smi, blk, tid);
    gbar(p.bar, (++nb) * 256u);
    phase_g2(p, i, smem, blk, tid);
    gbar(p.bar, (++nb) * 256u);
    phase_att(p, i, smem, blk, tid);
  }
  gbar(p.bar, (++nb) * 256u);
  // FIN: atts(63) + finalize(63)
  {
    int flat = blk * 256 + tid;
    int b = flat >> 11, t = flat & 2047;
    float s = fmaxf(p.Ssum[1 * 32 + b], 1e-12f);   // 63&1 == 1
    p.out[133120 + (size_t)(63 * 32 + b) * 2048 + t] = p.wbuf[b * 2048 + t] / s;
  }
  if (blk < 32 && tid < 64) do_finalize(p, 63, blk, tid);
}

extern "C" void kernel_launch(void* const* d_in, const int* in_sizes, int n_in,
                              void* d_out, int out_size, void* d_ws, size_t ws_size,
                              hipStream_t stream) {
  P p;
  p.listener = (const float*)d_in[0];
  p.outlen   = (const int*)d_in[1];
  p.ptgt     = (const int*)d_in[2];
  // d_in[3] = teacher_forcing (==1: coin uniform<1.0 always true -> always teacher-forced)
  p.embed = (const float*)d_in[4];
  p.W_ih1 = (const float*)d_in[5];  p.W_hh1 = (const float*)d_in[6];
  p.b_ih1 = (const float*)d_in[7];  p.b_hh1 = (const float*)d_in[8];
  p.W_ih2 = (const float*)d_in[9];  p.W_hh2 = (const float*)d_in[10];
  p.b_ih2 = (const float*)d_in[11]; p.b_hh2 = (const float*)d_in[12];
  p.W_s = (const float*)d_in[13]; p.b_s = (const float*)d_in[14];
  p.W_h = (const float*)d_in[15]; p.b_h = (const float*)d_in[16];
  p.W_v = (const float*)d_in[17]; p.b_v = (const float*)d_in[18];
  p.W_c = (const float*)d_in[19]; p.b_c = (const float*)d_in[20];
  p.h1_0 = (const float*)d_in[21]; p.c1_0 = (const float*)d_in[22];
  p.h2_0 = (const float*)d_in[23]; p.c2_0 = (const float*)d_in[24];

  char* w = (char*)d_ws;
  p.keyT   = (float*)w; w += (size_t)32 * 128 * 2048 * 4;   // 32 MB
  p.value  = (float*)w; w += (size_t)32 * 2048 * 128 * 4;   // 32 MB
  p.h1  = (float*)w; w += 2 * 32 * 512 * 4;
  p.c1  = (float*)w; w += 2 * 32 * 512 * 4;
  p.h2  = (float*)w; w += 2 * 32 * 512 * 4;
  p.c2  = (float*)w; w += 2 * 32 * 512 * 4;
  p.wbuf   = (float*)w; w += 32 * 2048 * 4;
  p.ctxnum = (float*)w; w += 2 * 32 * 128 * 4;
  p.Ssum   = (float*)w; w += 2 * 32 * 4;
  p.bar    = (unsigned*)w; w += 256;
  p.out = (float*)d_out;

  k_init<<<64, 256, 0, stream>>>(p);
  k_proj<<<4096, 256, 0, stream>>>(p);
  k_loop<<<256, 256, 0, stream>>>(p);
}

// Round 3
// 8416.521 us; speedup vs baseline: 1.3496x; 1.3496x over previous
//
#include <hip/hip_runtime.h>
#include <stdint.h>
#include <stddef.h>

// Problem dims (fixed): B=32 TENC=2048 LIS=512 HID=512 EMB=256 CLS=64 KEY=128 VAL=128 T=64 steps
// Outputs (f32, concat): logits [64,32,64] @0 ; preds.T [32,64] @131072 ; atts [64,32,2048] @133120
// Structure: k_init + k_proj + ONE persistent kernel (256 blocks x 1024 thr = 16 waves/CU, 4/SIMD)
// with a software grid barrier: release-add on 8 spread cachelines, RELAXED spin, one
// __threadfence() acquire after success (single L1/L2 invalidate per barrier).
//   per step i (1..63):  bar; G1 (gates1+act1, +atts(i-1), +finalize(i-1));
//                        bar; G2 (gates2+act2, +zero next-parity accum);
//                        bar; ATT (query, energies, exp, Ssum/ctxnum partials)
// State double-buffered by step parity: h1,c1,h2,c2,ctxnum,Ssum.

struct BarCtr { unsigned v; unsigned pad[31]; };  // 128 B apart

struct P {
  const float* listener; const int* outlen; const int* ptgt;
  const float* embed;
  const float *W_ih1, *W_hh1, *b_ih1, *b_hh1;
  const float *W_ih2, *W_hh2, *b_ih2, *b_hh2;
  const float *W_s, *b_s, *W_h, *b_h, *W_v, *b_v, *W_c, *b_c;
  const float *h1_0, *c1_0, *h2_0, *c2_0;
  float* keyT;            // [32][128][2048]
  float* value;           // [32][2048][128]
  float* h1;              // [2][32][512] ping-pong by step parity
  float* c1;              // [2][32][512]
  float* h2;              // [2][32][512]
  float* c2;              // [2][32][512]
  float* wbuf;            // [32][2048]
  float* ctxnum;          // [2][32][128]
  float* Ssum;            // [2][32]
  BarCtr* bar;            // 8 counters
  float* out;
};

__device__ __forceinline__ float sigf(float x) { return 1.0f / (1.0f + expf(-x)); }

// exact jax threefry2x32 (20 rounds)
__device__ __forceinline__ void tf2x32(uint32_t k0, uint32_t k1,
                                       uint32_t x0, uint32_t x1,
                                       uint32_t& o0, uint32_t& o1) {
  uint32_t k2 = k0 ^ k1 ^ 0x1BD11BDAu;
#define TFR(r) { x0 += x1; x1 = (x1 << (r)) | (x1 >> (32 - (r))); x1 ^= x0; }
  x0 += k0; x1 += k1;
  TFR(13) TFR(15) TFR(26) TFR(6)   x0 += k1; x1 += k2 + 1u;
  TFR(17) TFR(29) TFR(16) TFR(24)  x0 += k2; x1 += k0 + 2u;
  TFR(13) TFR(15) TFR(26) TFR(6)   x0 += k0; x1 += k1 + 3u;
  TFR(17) TFR(29) TFR(16) TFR(24)  x0 += k1; x1 += k2 + 4u;
  TFR(13) TFR(15) TFR(26) TFR(6)   x0 += k2; x1 += k0 + 5u;
#undef TFR
  o0 = x0; o1 = x1;
}

__device__ __forceinline__ float gumbel_f(uint32_t bits) {
  float f = __uint_as_float((bits >> 9) | 0x3f800000u) - 1.0f;
  float u = (f == 0.0f) ? 1.17549435e-38f : f;
  return -logf(-logf(u));
}

// ---- software grid barrier: 8-way spread arrival, relaxed spin, one acquire fence ----
__device__ __forceinline__ void gbar(BarCtr* bar, int blk, unsigned round) {
  __syncthreads();
  if (threadIdx.x == 0) {
    __hip_atomic_fetch_add(&bar[blk & 7].v, 1u, __ATOMIC_RELEASE, __HIP_MEMORY_SCOPE_AGENT);
    const unsigned tgt = round * 256u;
    for (;;) {
      unsigned s = 0;
#pragma unroll
      for (int c = 0; c < 8; ++c)
        s += __hip_atomic_load(&bar[c].v, __ATOMIC_RELAXED, __HIP_MEMORY_SCOPE_AGENT);
      if (s >= tgt) break;
      __builtin_amdgcn_s_sleep(4);
    }
    __threadfence();   // acquire: one L1/L2 invalidate so post-barrier reads are fresh
  }
  __syncthreads();
}

// ---------------- init: states (parity 0) + zero accumulators + barrier counters ----------------
__global__ void __launch_bounds__(256) k_init(P p) {
  int idx = blockIdx.x * 256 + threadIdx.x;   // grid 64*256 = 16384
  p.h1[idx] = p.h1_0[idx];
  p.c1[idx] = p.c1_0[idx];
  p.h2[idx] = p.h2_0[idx];
  p.c2[idx] = p.c2_0[idx];
  if (idx < 8192) p.ctxnum[idx] = 0.0f;
  if (idx < 64)   p.Ssum[idx]   = 0.0f;
  if (idx < 8)    p.bar[idx].v  = 0u;
}

// ---------------- hoisted projections: key_enc (f32, transposed) + value (f32) ----------------
__global__ void __launch_bounds__(256) k_proj(P p) {
  const int blk = blockIdx.x, tid = threadIdx.x;      // grid 4096
  const int b = blk >> 7, tb = blk & 127, t0 = tb * 16;
  __shared__ float lst[16 * 512];                     // 32 KB
  const float* src = p.listener + ((size_t)b * 2048 + t0) * 512;
  for (int n = 0; n < 32; ++n) {
    int idx = n * 256 + tid;
    lst[idx] = src[idx];
  }
  __syncthreads();
  const int c = tid;
  const float* wr = (c < 128) ? (p.W_h + c * 512) : (p.W_v + (c - 128) * 512);
  const float bias = (c < 128) ? p.b_h[c] : p.b_v[c - 128];
  float acc[16];
#pragma unroll
  for (int r = 0; r < 16; ++r) acc[r] = 0.0f;
  for (int k4 = 0; k4 < 128; ++k4) {
    float4 w4 = ((const float4*)wr)[k4];
#pragma unroll
    for (int r = 0; r < 16; ++r) {
      float4 x4 = ((const float4*)(lst + r * 512))[k4];
      acc[r] = fmaf(w4.x, x4.x, fmaf(w4.y, x4.y, fmaf(w4.z, x4.z, fmaf(w4.w, x4.w, acc[r]))));
    }
  }
  if (c < 128) {
#pragma unroll
    for (int r = 0; r < 16; ++r)
      p.keyT[((size_t)b * 128 + c) * 2048 + t0 + r] = acc[r] + bias;
  } else {
#pragma unroll
    for (int r = 0; r < 16; ++r)
      p.value[((size_t)b * 2048 + t0 + r) * 128 + (c - 128)] = acc[r] + bias;
  }
}

// ---------------- finalize step `step` for batch b: logits + categorical sample ----------------
// executed by one full wave (tid = 0..63); c = tid
__device__ void do_finalize(const P& p, int step, int b, int tid) {
  const int c = tid;
  const int par = step & 1;
  const float* h2p  = p.h2 + par * 16384 + b * 512;
  const float* ctxp = p.ctxnum + par * 4096 + b * 128;
  const float invS = 1.0f / fmaxf(p.Ssum[par * 32 + b], 1e-12f);
  const float* wr = p.W_c + c * 640;
  float a0 = 0.f, a1 = 0.f, a2 = 0.f, a3 = 0.f;
#pragma unroll 8
  for (int k4 = 0; k4 < 128; ++k4) {
    float4 w4 = ((const float4*)wr)[k4];
    float4 x4 = ((const float4*)h2p)[k4];
    a0 = fmaf(w4.x, x4.x, a0); a1 = fmaf(w4.y, x4.y, a1);
    a2 = fmaf(w4.z, x4.z, a2); a3 = fmaf(w4.w, x4.w, a3);
  }
#pragma unroll
  for (int k4 = 0; k4 < 32; ++k4) {
    float4 w4 = ((const float4*)(wr + 512))[k4];
    float4 x4 = ((const float4*)ctxp)[k4];
    a0 = fmaf(w4.x, x4.x * invS, a0); a1 = fmaf(w4.y, x4.y * invS, a1);
    a2 = fmaf(w4.z, x4.z * invS, a2); a3 = fmaf(w4.w, x4.w * invS, a3);
  }
  float lg = p.b_c[c] + ((a0 + a1) + (a2 + a3));
  p.out[(size_t)(step * 32 + b) * 64 + c] = lg;
  uint32_t n0, n1, r0, r1;
  tf2x32(0u, 2u, 0u, (uint32_t)step, n0, n1);          // fold_in(key(2), step)
  tf2x32(n0, n1, 0u, (uint32_t)(b * 64 + c), r0, r1);  // partitionable bits at pos b*64+c
  float z = gumbel_f(r0 ^ r1) + lg;
  int ix = c;
  for (int off = 32; off; off >>= 1) {
    float zz = __shfl_xor(z, off, 64); int ii = __shfl_xor(ix, off, 64);
    if (zz > z || (zz == z && ii < ix)) { z = zz; ix = ii; }
  }
  if (c == 0) p.out[131072 + b * 64 + step] = (float)ix;
}

// ---------------- phase G1 (1024 thr): gates1 + act1; + atts(i-1) + finalize(i-1) ----------------
// block owns j0=blk*2 -> 8 gate-rows; thread (q,m,b): q=K-quarter, m=row, b=batch
__device__ void phase_g1(const P& p, int i, float* smem, int* smi, int blk, int tid) {
  const int par = i & 1, q1 = par ^ 1;
  float* sx   = smem;          // 32*132 = 4224
  float* sp   = smem + 4224;   // 1024 partials
  float* sg   = smem + 5248;   // 256 gates
  float* sinv = smem + 5504;   // 32
  if (tid < 256) {   // atts output for step i-1
    int flat = blk * 256 + tid;
    int b = flat >> 11, t = flat & 2047;
    float s = fmaxf(p.Ssum[q1 * 32 + b], 1e-12f);
    p.out[133120 + (size_t)((i - 1) * 32 + b) * 2048 + t] = p.wbuf[b * 2048 + t] / s;
  }
  if (tid < 32) {
    sinv[tid] = 1.0f / fmaxf(p.Ssum[q1 * 32 + tid], 1e-12f);
    smi[tid]  = p.ptgt[tid * 65 + (i - 1)];   // teacher forcing == 1 always
  }
  const int b = tid & 31, m = (tid >> 5) & 7, q = tid >> 8;
  const int j0 = blk * 2;
  const int row = j0 + (m & 1) + (m >> 1) * 512;
  const float* h1r  = p.h1 + q1 * 16384;
  const float* ctxr = p.ctxnum + q1 * 4096;
  float a0 = 0.f, a1 = 0.f, a2 = 0.f, a3 = 0.f;
  for (int kt = 0; kt < 7; ++kt) {   // K = 896 = 2*128 emb + 128 ctx + 4*128 h1
    __syncthreads();
#pragma unroll
    for (int n = 0; n < 4; ++n) {
      int idx = n * 1024 + tid, fb = idx >> 7, kk = idx & 127;
      float v;
      if (kt < 2)       v = p.embed[smi[fb] * 256 + kt * 128 + kk];
      else if (kt == 2) v = ctxr[fb * 128 + kk] * sinv[fb];
      else              v = h1r[fb * 512 + (kt - 3) * 128 + kk];
      sx[fb * 132 + kk] = v;
    }
    __syncthreads();
    const float* wr = (kt < 3) ? (p.W_ih1 + row * 384 + kt * 128)
                               : (p.W_hh1 + row * 512 + (kt - 3) * 128);
    const float4* w4p = (const float4*)(wr + q * 32);
    const float4* x4p = (const float4*)(sx + b * 132 + q * 32);
#pragma unroll
    for (int k4 = 0; k4 < 8; ++k4) {
      float4 w4 = w4p[k4], x4 = x4p[k4];
      a0 = fmaf(w4.x, x4.x, a0); a1 = fmaf(w4.y, x4.y, a1);
      a2 = fmaf(w4.z, x4.z, a2); a3 = fmaf(w4.w, x4.w, a3);
    }
  }
  sp[q * 256 + m * 32 + b] = (a0 + a1) + (a2 + a3);
  __syncthreads();
  if (tid < 256) {
    int mm = tid >> 5;
    int rr = j0 + (mm & 1) + (mm >> 1) * 512;
    sg[tid] = sp[tid] + sp[256 + tid] + sp[512 + tid] + sp[768 + tid]
            + p.b_ih1[rr] + p.b_hh1[rr];
  }
  __syncthreads();
  if (tid < 64) {
    int jl = tid >> 5, bb = tid & 31, j = j0 + jl;
    float gi = sg[(0 + jl) * 32 + bb];
    float gf = sg[(2 + jl) * 32 + bb];
    float gg = sg[(4 + jl) * 32 + bb];
    float go = sg[(6 + jl) * 32 + bb];
    float cp = p.c1[q1 * 16384 + bb * 512 + j];
    float c  = sigf(gf) * cp + sigf(gi) * tanhf(gg);
    p.h1[par * 16384 + bb * 512 + j] = sigf(go) * tanhf(c);
    p.c1[par * 16384 + bb * 512 + j] = c;
  }
  if (blk < 32 && tid < 64) do_finalize(p, i - 1, blk, tid);
}

// ---------------- phase G2 (1024 thr): gates2 + act2; + zero next-parity accumulators ----------------
__device__ void phase_g2(const P& p, int i, float* smem, int blk, int tid) {
  const int par = i & 1, q1 = par ^ 1;
  float* sx = smem;
  float* sp = smem + 4224;
  float* sg = smem + 5248;
  // zero parity-q1 accumulators for ATT(i+1) (dead now: G1(i)/finalize(i-1) consumed them)
  if (blk < 4) p.ctxnum[q1 * 4096 + blk * 1024 + tid] = 0.0f;
  if (blk == 4 && tid < 32) p.Ssum[q1 * 32 + tid] = 0.0f;
  const int b = tid & 31, m = (tid >> 5) & 7, q = tid >> 8;
  const int j0 = blk * 2;
  const int row = j0 + (m & 1) + (m >> 1) * 512;
  const float* h1r = p.h1 + par * 16384;
  const float* h2r = p.h2 + q1 * 16384;
  float a0 = 0.f, a1 = 0.f, a2 = 0.f, a3 = 0.f;
  for (int kt = 0; kt < 8; ++kt) {  // K = 1024 = 4*128 h1 + 4*128 h2prev
    __syncthreads();
#pragma unroll
    for (int n = 0; n < 4; ++n) {
      int idx = n * 1024 + tid, fb = idx >> 7, kk = idx & 127;
      float v = (kt < 4) ? h1r[fb * 512 + kt * 128 + kk]
                         : h2r[fb * 512 + (kt - 4) * 128 + kk];
      sx[fb * 132 + kk] = v;
    }
    __syncthreads();
    const float* wr = (kt < 4) ? (p.W_ih2 + row * 512 + kt * 128)
                               : (p.W_hh2 + row * 512 + (kt - 4) * 128);
    const float4* w4p = (const float4*)(wr + q * 32);
    const float4* x4p = (const float4*)(sx + b * 132 + q * 32);
#pragma unroll
    for (int k4 = 0; k4 < 8; ++k4) {
      float4 w4 = w4p[k4], x4 = x4p[k4];
      a0 = fmaf(w4.x, x4.x, a0); a1 = fmaf(w4.y, x4.y, a1);
      a2 = fmaf(w4.z, x4.z, a2); a3 = fmaf(w4.w, x4.w, a3);
    }
  }
  sp[q * 256 + m * 32 + b] = (a0 + a1) + (a2 + a3);
  __syncthreads();
  if (tid < 256) {
    int mm = tid >> 5;
    int rr = j0 + (mm & 1) + (mm >> 1) * 512;
    sg[tid] = sp[tid] + sp[256 + tid] + sp[512 + tid] + sp[768 + tid]
            + p.b_ih2[rr] + p.b_hh2[rr];
  }
  __syncthreads();
  if (tid < 64) {
    int jl = tid >> 5, bb = tid & 31, j = j0 + jl;
    float gi = sg[(0 + jl) * 32 + bb];
    float gf = sg[(2 + jl) * 32 + bb];
    float gg = sg[(4 + jl) * 32 + bb];
    float go = sg[(6 + jl) * 32 + bb];
    float cp = p.c2[q1 * 16384 + bb * 512 + j];
    float c  = sigf(gf) * cp + sigf(gi) * tanhf(gg);
    p.h2[par * 16384 + bb * 512 + j] = sigf(go) * tanhf(c);
    p.c2[par * 16384 + bb * 512 + j] = c;
  }
}

// ---------------- phase ATT (1024 thr): query, energies, exp*mask, Ssum & ctxnum partials ----------------
// 256 blocks = 32 b x 8 chunks of 256 t
__device__ void phase_att(const P& p, int i, float* smem, int blk, int tid) {
  const int par = i & 1;
  const int b = blk >> 3, ch = blk & 7, t0 = ch * 256;
  float* sh2 = smem;          // 512
  float* sq  = smem + 512;    // 128
  float* sqp = smem + 640;    // 512
  float* se  = smem + 1152;   // 1024
  float* sw  = smem + 2176;   // 256
  float* swr = smem + 2432;   // 8
  float* sc  = smem + 2440;   // 1024
  const float* h2p = p.h2 + par * 16384 + b * 512;
  if (tid < 512) sh2[tid] = h2p[tid];
  __syncthreads();
  if (tid < 512) {  // query partials: (col, K-quarter)
    int col = tid & 127, qh = tid >> 7;
    const float* wr = p.W_s + col * 512 + qh * 128;
    const float4* h4p = (const float4*)(sh2 + qh * 128);
    float a0 = 0.f, a1 = 0.f, a2 = 0.f, a3 = 0.f;
#pragma unroll
    for (int j4 = 0; j4 < 32; ++j4) {
      float4 w4 = ((const float4*)wr)[j4], h4 = h4p[j4];
      a0 = fmaf(w4.x, h4.x, a0); a1 = fmaf(w4.y, h4.y, a1);
      a2 = fmaf(w4.z, h4.z, a2); a3 = fmaf(w4.w, h4.w, a3);
    }
    sqp[qh * 128 + col] = (a0 + a1) + (a2 + a3);
  }
  __syncthreads();
  if (tid < 128) sq[tid] = p.b_s[tid] + sqp[tid] + sqp[128 + tid] + sqp[256 + tid] + sqp[384 + tid];
  __syncthreads();
  {  // energy partials: (t, K-quarter of 32)
    int tt = tid & 255, kq = tid >> 8;
    const float* kc = p.keyT + (size_t)b * 262144 + (t0 + tt);
    const int kb = kq * 32;
    float e0 = 0.f, e1 = 0.f, e2 = 0.f, e3 = 0.f;
#pragma unroll 8
    for (int k = 0; k < 32; k += 4) {
      e0 = fmaf(kc[(size_t)(kb + k + 0) * 2048], sq[kb + k + 0], e0);
      e1 = fmaf(kc[(size_t)(kb + k + 1) * 2048], sq[kb + k + 1], e1);
      e2 = fmaf(kc[(size_t)(kb + k + 2) * 2048], sq[kb + k + 2], e2);
      e3 = fmaf(kc[(size_t)(kb + k + 3) * 2048], sq[kb + k + 3], e3);
    }
    se[kq * 256 + tt] = (e0 + e1) + (e2 + e3);
  }
  __syncthreads();
  if (tid < 256) {
    int t = t0 + tid;
    float e = se[tid] + se[256 + tid] + se[512 + tid] + se[768 + tid];
    const int len = p.outlen[b];
    bool msk = (b == 0) || (t < len);
    float wv = msk ? expf(e) : 0.0f;
    p.wbuf[b * 2048 + t] = wv;
    sw[tid] = wv;
    float s = wv;
    for (int off = 32; off; off >>= 1) s += __shfl_xor(s, off, 64);
    if ((tid & 63) == 0) swr[tid >> 6] = s;
  }
  __syncthreads();
  if (tid == 0) atomicAdd(&p.Ssum[par * 32 + b], swr[0] + swr[1] + swr[2] + swr[3]);
  {  // ctx partials: (v, t-octant of 32)
    int v = tid & 127, tp = tid >> 7;
    const float* vb = p.value + ((size_t)(b * 2048 + t0 + tp * 32)) * 128 + v;
    float c0 = 0.f, c1v = 0.f;
#pragma unroll 8
    for (int tt2 = 0; tt2 < 32; tt2 += 2) {
      c0  = fmaf(sw[tp * 32 + tt2],     vb[(size_t)tt2 * 128],       c0);
      c1v = fmaf(sw[tp * 32 + tt2 + 1], vb[(size_t)(tt2 + 1) * 128], c1v);
    }
    sc[tp * 128 + v] = c0 + c1v;
  }
  __syncthreads();
  if (tid < 128) {
    float s = 0.f;
#pragma unroll
    for (int tp = 0; tp < 8; ++tp) s += sc[tp * 128 + tid];
    atomicAdd(&p.ctxnum[par * 4096 + b * 128 + tid], s);
  }
}

// ---------------- the persistent decode loop ----------------
__global__ void __launch_bounds__(1024, 4) k_loop(P p) {
  __shared__ float smem[5600];
  __shared__ int   smi[32];
  const int blk = blockIdx.x, tid = threadIdx.x;
  unsigned nb = 0;
  phase_att(p, 0, smem, blk, tid);
  for (int i = 1; i < 64; ++i) {
    gbar(p.bar, blk, ++nb);
    phase_g1(p, i, smem, smi, blk, tid);
    gbar(p.bar, blk, ++nb);
    phase_g2(p, i, smem, blk, tid);
    gbar(p.bar, blk, ++nb);
    phase_att(p, i, smem, blk, tid);
  }
  gbar(p.bar, blk, ++nb);
  // FIN: atts(63) + finalize(63)
  if (tid < 256) {
    int flat = blk * 256 + tid;
    int b = flat >> 11, t = flat & 2047;
    float s = fmaxf(p.Ssum[1 * 32 + b], 1e-12f);   // 63&1 == 1
    p.out[133120 + (size_t)(63 * 32 + b) * 2048 + t] = p.wbuf[b * 2048 + t] / s;
  }
  if (blk < 32 && tid < 64) do_finalize(p, 63, blk, tid);
}

extern "C" void kernel_launch(void* const* d_in, const int* in_sizes, int n_in,
                              void* d_out, int out_size, void* d_ws, size_t ws_size,
                              hipStream_t stream) {
  P p;
  p.listener = (const float*)d_in[0];
  p.outlen   = (const int*)d_in[1];
  p.ptgt     = (const int*)d_in[2];
  // d_in[3] = teacher_forcing (==1: always teacher-forced)
  p.embed = (const float*)d_in[4];
  p.W_ih1 = (const float*)d_in[5];  p.W_hh1 = (const float*)d_in[6];
  p.b_ih1 = (const float*)d_in[7];  p.b_hh1 = (const float*)d_in[8];
  p.W_ih2 = (const float*)d_in[9];  p.W_hh2 = (const float*)d_in[10];
  p.b_ih2 = (const float*)d_in[11]; p.b_hh2 = (const float*)d_in[12];
  p.W_s = (const float*)d_in[13]; p.b_s = (const float*)d_in[14];
  p.W_h = (const float*)d_in[15]; p.b_h = (const float*)d_in[16];
  p.W_v = (const float*)d_in[17]; p.b_v = (const float*)d_in[18];
  p.W_c = (const float*)d_in[19]; p.b_c = (const float*)d_in[20];
  p.h1_0 = (const float*)d_in[21]; p.c1_0 = (const float*)d_in[22];
  p.h2_0 = (const float*)d_in[23]; p.c2_0 = (const float*)d_in[24];

  char* w = (char*)d_ws;
  p.keyT   = (float*)w; w += (size_t)32 * 128 * 2048 * 4;   // 32 MB
  p.value  = (float*)w; w += (size_t)32 * 2048 * 128 * 4;   // 32 MB
  p.h1  = (float*)w; w += 2 * 32 * 512 * 4;
  p.c1  = (float*)w; w += 2 * 32 * 512 * 4;
  p.h2  = (float*)w; w += 2 * 32 * 512 * 4;
  p.c2  = (float*)w; w += 2 * 32 * 512 * 4;
  p.wbuf   = (float*)w; w += 32 * 2048 * 4;
  p.ctxnum = (float*)w; w += 2 * 32 * 128 * 4;
  p.Ssum   = (float*)w; w += 2 * 32 * 4;
  p.bar    = (BarCtr*)w; w += 8 * sizeof(BarCtr);
  p.out = (float*)d_out;

  k_init<<<64, 256, 0, stream>>>(p);
  k_proj<<<4096, 256, 0, stream>>>(p);
  k_loop<<<256, 1024, 0, stream>>>(p);
}

// Round 4
// 6741.531 us; speedup vs baseline: 1.6849x; 1.2485x over previous
//
#include <hip/hip_runtime.h>
#include <stdint.h>
#include <stddef.h>

// Problem dims (fixed): B=32 TENC=2048 LIS=512 HID=512 EMB=256 CLS=64 KEY=128 VAL=128 T=64 steps
// Outputs (f32, concat): logits [64,32,64] @0 ; preds.T [32,64] @131072 ; atts [64,32,2048] @133120
// Structure: k_init + k_proj + ONE persistent kernel (256 blocks x 1024 thr).
// Cross-block mutable state (h1,h2,ctxnum,Ssum,wbuf,bar) goes through relaxed AGENT-scope atomics
// (device-coherence-point accesses, no cache-wide invalidates). Read-only data (weights, keyT,
// value) uses plain loads and stays hot in L1/L2 across all steps. Barrier = syncthreads (drains
// vmem) + relaxed add on 8 spread cachelines + relaxed spin; NO threadfence (nothing to invalidate).
//   per step i (1..63):  bar; G1 (gates1+act1, +atts(i-1), +finalize(i-1));
//                        bar; G2 (gates2+act2, +zero next-parity accum);
//                        bar; ATT (query, energies, exp, Ssum/ctxnum partials)
// State double-buffered by step parity: h1,c1,h2,c2,ctxnum,Ssum. c1/c2 are block-private (plain).

struct BarCtr { unsigned v; unsigned pad[31]; };  // 128 B apart

struct P {
  const float* listener; const int* outlen; const int* ptgt;
  const float* embed;
  const float *W_ih1, *W_hh1, *b_ih1, *b_hh1;
  const float *W_ih2, *W_hh2, *b_ih2, *b_hh2;
  const float *W_s, *b_s, *W_h, *b_h, *W_v, *b_v, *W_c, *b_c;
  const float *h1_0, *c1_0, *h2_0, *c2_0;
  float* keyT;            // [32][128][2048]
  float* value;           // [32][2048][128]
  float* h1;              // [2][32][512] ping-pong by step parity (cross-block -> atomics)
  float* c1;              // [2][32][512] block-private (plain)
  float* h2;              // [2][32][512] cross-block -> atomics
  float* c2;              // [2][32][512] block-private (plain)
  float* wbuf;            // [32][2048]  cross-block -> atomics
  float* ctxnum;          // [2][32][128] cross-block -> atomics
  float* Ssum;            // [2][32]      cross-block -> atomics
  BarCtr* bar;            // 8 counters
  float* out;
};

__device__ __forceinline__ float sigf(float x) { return 1.0f / (1.0f + expf(-x)); }

__device__ __forceinline__ float gload(const float* p) {
  return __hip_atomic_load(p, __ATOMIC_RELAXED, __HIP_MEMORY_SCOPE_AGENT);
}
__device__ __forceinline__ void gstore(float* p, float v) {
  __hip_atomic_store(p, v, __ATOMIC_RELAXED, __HIP_MEMORY_SCOPE_AGENT);
}
__device__ __forceinline__ void gadd(float* p, float v) {
  __hip_atomic_fetch_add(p, v, __ATOMIC_RELAXED, __HIP_MEMORY_SCOPE_AGENT);
}

// exact jax threefry2x32 (20 rounds)
__device__ __forceinline__ void tf2x32(uint32_t k0, uint32_t k1,
                                       uint32_t x0, uint32_t x1,
                                       uint32_t& o0, uint32_t& o1) {
  uint32_t k2 = k0 ^ k1 ^ 0x1BD11BDAu;
#define TFR(r) { x0 += x1; x1 = (x1 << (r)) | (x1 >> (32 - (r))); x1 ^= x0; }
  x0 += k0; x1 += k1;
  TFR(13) TFR(15) TFR(26) TFR(6)   x0 += k1; x1 += k2 + 1u;
  TFR(17) TFR(29) TFR(16) TFR(24)  x0 += k2; x1 += k0 + 2u;
  TFR(13) TFR(15) TFR(26) TFR(6)   x0 += k0; x1 += k1 + 3u;
  TFR(17) TFR(29) TFR(16) TFR(24)  x0 += k1; x1 += k2 + 4u;
  TFR(13) TFR(15) TFR(26) TFR(6)   x0 += k2; x1 += k0 + 5u;
#undef TFR
  o0 = x0; o1 = x1;
}

__device__ __forceinline__ float gumbel_f(uint32_t bits) {
  float f = __uint_as_float((bits >> 9) | 0x3f800000u) - 1.0f;
  float u = (f == 0.0f) ? 1.17549435e-38f : f;
  return -logf(-logf(u));
}

// ---- software grid barrier: NO cache maintenance (all shared data goes via agent atomics) ----
__device__ __forceinline__ void gbar(BarCtr* bar, int blk, unsigned round) {
  __syncthreads();   // compiler emits full s_waitcnt before s_barrier: block's vmem drained
  if (threadIdx.x == 0) {
    __hip_atomic_fetch_add(&bar[blk & 7].v, 1u, __ATOMIC_RELAXED, __HIP_MEMORY_SCOPE_AGENT);
    const unsigned tgt = round * 256u;
    for (;;) {
      unsigned s = 0;
#pragma unroll
      for (int c = 0; c < 8; ++c)
        s += __hip_atomic_load(&bar[c].v, __ATOMIC_RELAXED, __HIP_MEMORY_SCOPE_AGENT);
      if (s >= tgt) break;
      __builtin_amdgcn_s_sleep(1);
    }
    asm volatile("" ::: "memory");   // pin compiler ordering; no HW invalidate needed
  }
  __syncthreads();
}

// ---------------- init: states (parity 0) + zero accumulators + barrier counters ----------------
__global__ void __launch_bounds__(256) k_init(P p) {
  int idx = blockIdx.x * 256 + threadIdx.x;   // grid 64*256 = 16384
  p.h1[idx] = p.h1_0[idx];
  p.c1[idx] = p.c1_0[idx];
  p.h2[idx] = p.h2_0[idx];
  p.c2[idx] = p.c2_0[idx];
  if (idx < 8192) p.ctxnum[idx] = 0.0f;
  if (idx < 64)   p.Ssum[idx]   = 0.0f;
  if (idx < 8)    p.bar[idx].v  = 0u;
}

// ---------------- hoisted projections: key_enc (f32, transposed) + value (f32) ----------------
__global__ void __launch_bounds__(256) k_proj(P p) {
  const int blk = blockIdx.x, tid = threadIdx.x;      // grid 4096
  const int b = blk >> 7, tb = blk & 127, t0 = tb * 16;
  __shared__ float lst[16 * 512];                     // 32 KB
  const float* src = p.listener + ((size_t)b * 2048 + t0) * 512;
  for (int n = 0; n < 32; ++n) {
    int idx = n * 256 + tid;
    lst[idx] = src[idx];
  }
  __syncthreads();
  const int c = tid;
  const float* wr = (c < 128) ? (p.W_h + c * 512) : (p.W_v + (c - 128) * 512);
  const float bias = (c < 128) ? p.b_h[c] : p.b_v[c - 128];
  float acc[16];
#pragma unroll
  for (int r = 0; r < 16; ++r) acc[r] = 0.0f;
  for (int k4 = 0; k4 < 128; ++k4) {
    float4 w4 = ((const float4*)wr)[k4];
#pragma unroll
    for (int r = 0; r < 16; ++r) {
      float4 x4 = ((const float4*)(lst + r * 512))[k4];
      acc[r] = fmaf(w4.x, x4.x, fmaf(w4.y, x4.y, fmaf(w4.z, x4.z, fmaf(w4.w, x4.w, acc[r]))));
    }
  }
  if (c < 128) {
#pragma unroll
    for (int r = 0; r < 16; ++r)
      p.keyT[((size_t)b * 128 + c) * 2048 + t0 + r] = acc[r] + bias;
  } else {
#pragma unroll
    for (int r = 0; r < 16; ++r)
      p.value[((size_t)b * 2048 + t0 + r) * 128 + (c - 128)] = acc[r] + bias;
  }
}

// ---------------- finalize step `step` for batch b: logits + categorical sample ----------------
// executed by one full wave (tid = 0..63); sf = 640-float LDS scratch for this block
__device__ void do_finalize(const P& p, int step, int b, int tid, float* sf) {
  const int c = tid;
  const int par = step & 1;
  const float* h2p  = p.h2 + par * 16384 + b * 512;
  const float* ctxp = p.ctxnum + par * 4096 + b * 128;
  const float invS = 1.0f / fmaxf(gload(&p.Ssum[par * 32 + b]), 1e-12f);
  // wave-cooperative stage of [h2 | ctx*invS] into LDS (distinct addresses per lane)
#pragma unroll
  for (int n = 0; n < 10; ++n) {
    int idx = n * 64 + c;
    float v = (idx < 512) ? gload(&h2p[idx]) : gload(&ctxp[idx - 512]) * invS;
    sf[idx] = v;
  }
  asm volatile("s_waitcnt vmcnt(0) lgkmcnt(0)" ::: "memory");
  __builtin_amdgcn_wave_barrier();
  const float* wr = p.W_c + c * 640;
  float a0 = 0.f, a1 = 0.f, a2 = 0.f, a3 = 0.f;
#pragma unroll 8
  for (int k4 = 0; k4 < 160; ++k4) {
    float4 w4 = ((const float4*)wr)[k4];
    float4 x4 = ((const float4*)sf)[k4];
    a0 = fmaf(w4.x, x4.x, a0); a1 = fmaf(w4.y, x4.y, a1);
    a2 = fmaf(w4.z, x4.z, a2); a3 = fmaf(w4.w, x4.w, a3);
  }
  float lg = p.b_c[c] + ((a0 + a1) + (a2 + a3));
  p.out[(size_t)(step * 32 + b) * 64 + c] = lg;
  uint32_t n0, n1, r0, r1;
  tf2x32(0u, 2u, 0u, (uint32_t)step, n0, n1);          // fold_in(key(2), step)
  tf2x32(n0, n1, 0u, (uint32_t)(b * 64 + c), r0, r1);  // partitionable bits at pos b*64+c
  float z = gumbel_f(r0 ^ r1) + lg;
  int ix = c;
  for (int off = 32; off; off >>= 1) {
    float zz = __shfl_xor(z, off, 64); int ii = __shfl_xor(ix, off, 64);
    if (zz > z || (zz == z && ii < ix)) { z = zz; ix = ii; }
  }
  if (c == 0) p.out[131072 + b * 64 + step] = (float)ix;
}

// ---------------- phase G1 (1024 thr): gates1 + act1; + atts(i-1) + finalize(i-1) ----------------
// block owns j0=blk*2 -> 8 gate-rows; thread (q,m,b): q=K-quarter, m=row, b=batch
__device__ void phase_g1(const P& p, int i, float* smem, int* smi, float* sf, int blk, int tid) {
  const int par = i & 1, q1 = par ^ 1;
  float* sx   = smem;          // 32*132 = 4224
  float* sp   = smem + 4224;   // 1024 partials
  float* sg   = smem + 5248;   // 256 gates
  float* sinv = smem + 5504;   // 32
  if (tid < 256) {   // atts output for step i-1
    int flat = blk * 256 + tid;
    int b = flat >> 11, t = flat & 2047;
    float s = fmaxf(gload(&p.Ssum[q1 * 32 + b]), 1e-12f);
    p.out[133120 + (size_t)((i - 1) * 32 + b) * 2048 + t] = gload(&p.wbuf[b * 2048 + t]) / s;
  }
  if (tid < 32) {
    sinv[tid] = 1.0f / fmaxf(gload(&p.Ssum[q1 * 32 + tid]), 1e-12f);
    smi[tid]  = p.ptgt[tid * 65 + (i - 1)];   // teacher forcing == 1 always
  }
  const int b = tid & 31, m = (tid >> 5) & 7, q = tid >> 8;
  const int j0 = blk * 2;
  const int row = j0 + (m & 1) + (m >> 1) * 512;
  const float* h1r  = p.h1 + q1 * 16384;
  const float* ctxr = p.ctxnum + q1 * 4096;
  float a0 = 0.f, a1 = 0.f, a2 = 0.f, a3 = 0.f;
  for (int kt = 0; kt < 7; ++kt) {   // K = 896 = 2*128 emb + 128 ctx + 4*128 h1
    __syncthreads();
#pragma unroll
    for (int n = 0; n < 4; ++n) {
      int idx = n * 1024 + tid, fb = idx >> 7, kk = idx & 127;
      float v;
      if (kt < 2)       v = p.embed[smi[fb] * 256 + kt * 128 + kk];
      else if (kt == 2) v = gload(&ctxr[fb * 128 + kk]) * sinv[fb];
      else              v = gload(&h1r[fb * 512 + (kt - 3) * 128 + kk]);
      sx[fb * 132 + kk] = v;
    }
    __syncthreads();
    const float* wr = (kt < 3) ? (p.W_ih1 + row * 384 + kt * 128)
                               : (p.W_hh1 + row * 512 + (kt - 3) * 128);
    const float4* w4p = (const float4*)(wr + q * 32);
    const float4* x4p = (const float4*)(sx + b * 132 + q * 32);
#pragma unroll
    for (int k4 = 0; k4 < 8; ++k4) {
      float4 w4 = w4p[k4], x4 = x4p[k4];
      a0 = fmaf(w4.x, x4.x, a0); a1 = fmaf(w4.y, x4.y, a1);
      a2 = fmaf(w4.z, x4.z, a2); a3 = fmaf(w4.w, x4.w, a3);
    }
  }
  sp[q * 256 + m * 32 + b] = (a0 + a1) + (a2 + a3);
  __syncthreads();
  if (tid < 256) {
    int mm = tid >> 5;
    int rr = j0 + (mm & 1) + (mm >> 1) * 512;
    sg[tid] = sp[tid] + sp[256 + tid] + sp[512 + tid] + sp[768 + tid]
            + p.b_ih1[rr] + p.b_hh1[rr];
  }
  __syncthreads();
  if (tid < 64) {
    int jl = tid >> 5, bb = tid & 31, j = j0 + jl;
    float gi = sg[(0 + jl) * 32 + bb];
    float gf = sg[(2 + jl) * 32 + bb];
    float gg = sg[(4 + jl) * 32 + bb];
    float go = sg[(6 + jl) * 32 + bb];
    float cp = p.c1[q1 * 16384 + bb * 512 + j];           // block-private: plain
    float c  = sigf(gf) * cp + sigf(gi) * tanhf(gg);
    gstore(&p.h1[par * 16384 + bb * 512 + j], sigf(go) * tanhf(c));
    p.c1[par * 16384 + bb * 512 + j] = c;                 // block-private: plain
  }
  if (blk < 32 && tid < 64) do_finalize(p, i - 1, blk, tid, sf);
}

// ---------------- phase G2 (1024 thr): gates2 + act2; + zero next-parity accumulators ----------------
__device__ void phase_g2(const P& p, int i, float* smem, int blk, int tid) {
  const int par = i & 1, q1 = par ^ 1;
  float* sx = smem;
  float* sp = smem + 4224;
  float* sg = smem + 5248;
  // zero parity-q1 accumulators for ATT(i+1) (dead now: G1(i)/finalize(i-1) consumed them)
  if (blk < 4) gstore(&p.ctxnum[q1 * 4096 + blk * 1024 + tid], 0.0f);
  if (blk == 4 && tid < 32) gstore(&p.Ssum[q1 * 32 + tid], 0.0f);
  const int b = tid & 31, m = (tid >> 5) & 7, q = tid >> 8;
  const int j0 = blk * 2;
  const int row = j0 + (m & 1) + (m >> 1) * 512;
  const float* h1r = p.h1 + par * 16384;
  const float* h2r = p.h2 + q1 * 16384;
  float a0 = 0.f, a1 = 0.f, a2 = 0.f, a3 = 0.f;
  for (int kt = 0; kt < 8; ++kt) {  // K = 1024 = 4*128 h1 + 4*128 h2prev
    __syncthreads();
#pragma unroll
    for (int n = 0; n < 4; ++n) {
      int idx = n * 1024 + tid, fb = idx >> 7, kk = idx & 127;
      float v = (kt < 4) ? gload(&h1r[fb * 512 + kt * 128 + kk])
                         : gload(&h2r[fb * 512 + (kt - 4) * 128 + kk]);
      sx[fb * 132 + kk] = v;
    }
    __syncthreads();
    const float* wr = (kt < 4) ? (p.W_ih2 + row * 512 + kt * 128)
                               : (p.W_hh2 + row * 512 + (kt - 4) * 128);
    const float4* w4p = (const float4*)(wr + q * 32);
    const float4* x4p = (const float4*)(sx + b * 132 + q * 32);
#pragma unroll
    for (int k4 = 0; k4 < 8; ++k4) {
      float4 w4 = w4p[k4], x4 = x4p[k4];
      a0 = fmaf(w4.x, x4.x, a0); a1 = fmaf(w4.y, x4.y, a1);
      a2 = fmaf(w4.z, x4.z, a2); a3 = fmaf(w4.w, x4.w, a3);
    }
  }
  sp[q * 256 + m * 32 + b] = (a0 + a1) + (a2 + a3);
  __syncthreads();
  if (tid < 256) {
    int mm = tid >> 5;
    int rr = j0 + (mm & 1) + (mm >> 1) * 512;
    sg[tid] = sp[tid] + sp[256 + tid] + sp[512 + tid] + sp[768 + tid]
            + p.b_ih2[rr] + p.b_hh2[rr];
  }
  __syncthreads();
  if (tid < 64) {
    int jl = tid >> 5, bb = tid & 31, j = j0 + jl;
    float gi = sg[(0 + jl) * 32 + bb];
    float gf = sg[(2 + jl) * 32 + bb];
    float gg = sg[(4 + jl) * 32 + bb];
    float go = sg[(6 + jl) * 32 + bb];
    float cp = p.c2[q1 * 16384 + bb * 512 + j];           // block-private: plain
    float c  = sigf(gf) * cp + sigf(gi) * tanhf(gg);
    gstore(&p.h2[par * 16384 + bb * 512 + j], sigf(go) * tanhf(c));
    p.c2[par * 16384 + bb * 512 + j] = c;                 // block-private: plain
  }
}

// ---------------- phase ATT (1024 thr): query, energies, exp*mask, Ssum & ctxnum partials ----------------
// 256 blocks = 32 b x 8 chunks of 256 t
__device__ void phase_att(const P& p, int i, float* smem, int blk, int tid) {
  const int par = i & 1;
  const int b = blk >> 3, ch = blk & 7, t0 = ch * 256;
  float* sh2 = smem;          // 512
  float* sq  = smem + 512;    // 128
  float* sqp = smem + 640;    // 512
  float* se  = smem + 1152;   // 1024
  float* sw  = smem + 2176;   // 256
  float* swr = smem + 2432;   // 8
  float* sc  = smem + 2440;   // 1024
  const float* h2p = p.h2 + par * 16384 + b * 512;
  if (tid < 512) sh2[tid] = gload(&h2p[tid]);
  __syncthreads();
  if (tid < 512) {  // query partials: (col, K-quarter)
    int col = tid & 127, qh = tid >> 7;
    const float* wr = p.W_s + col * 512 + qh * 128;
    const float4* h4p = (const float4*)(sh2 + qh * 128);
    float a0 = 0.f, a1 = 0.f, a2 = 0.f, a3 = 0.f;
#pragma unroll
    for (int j4 = 0; j4 < 32; ++j4) {
      float4 w4 = ((const float4*)wr)[j4], h4 = h4p[j4];
      a0 = fmaf(w4.x, h4.x, a0); a1 = fmaf(w4.y, h4.y, a1);
      a2 = fmaf(w4.z, h4.z, a2); a3 = fmaf(w4.w, h4.w, a3);
    }
    sqp[qh * 128 + col] = (a0 + a1) + (a2 + a3);
  }
  __syncthreads();
  if (tid < 128) sq[tid] = p.b_s[tid] + sqp[tid] + sqp[128 + tid] + sqp[256 + tid] + sqp[384 + tid];
  __syncthreads();
  {  // energy partials: (t, K-quarter of 32)
    int tt = tid & 255, kq = tid >> 8;
    const float* kc = p.keyT + (size_t)b * 262144 + (t0 + tt);
    const int kb = kq * 32;
    float e0 = 0.f, e1 = 0.f, e2 = 0.f, e3 = 0.f;
#pragma unroll 8
    for (int k = 0; k < 32; k += 4) {
      e0 = fmaf(kc[(size_t)(kb + k + 0) * 2048], sq[kb + k + 0], e0);
      e1 = fmaf(kc[(size_t)(kb + k + 1) * 2048], sq[kb + k + 1], e1);
      e2 = fmaf(kc[(size_t)(kb + k + 2) * 2048], sq[kb + k + 2], e2);
      e3 = fmaf(kc[(size_t)(kb + k + 3) * 2048], sq[kb + k + 3], e3);
    }
    se[kq * 256 + tt] = (e0 + e1) + (e2 + e3);
  }
  __syncthreads();
  if (tid < 256) {
    int t = t0 + tid;
    float e = se[tid] + se[256 + tid] + se[512 + tid] + se[768 + tid];
    const int len = p.outlen[b];
    bool msk = (b == 0) || (t < len);
    float wv = msk ? expf(e) : 0.0f;
    gstore(&p.wbuf[b * 2048 + t], wv);
    sw[tid] = wv;
    float s = wv;
    for (int off = 32; off; off >>= 1) s += __shfl_xor(s, off, 64);
    if ((tid & 63) == 0) swr[tid >> 6] = s;
  }
  __syncthreads();
  if (tid == 0) gadd(&p.Ssum[par * 32 + b], swr[0] + swr[1] + swr[2] + swr[3]);
  {  // ctx partials: (v, t-octant of 32)
    int v = tid & 127, tp = tid >> 7;
    const float* vb = p.value + ((size_t)(b * 2048 + t0 + tp * 32)) * 128 + v;
    float c0 = 0.f, c1v = 0.f;
#pragma unroll 8
    for (int tt2 = 0; tt2 < 32; tt2 += 2) {
      c0  = fmaf(sw[tp * 32 + tt2],     vb[(size_t)tt2 * 128],       c0);
      c1v = fmaf(sw[tp * 32 + tt2 + 1], vb[(size_t)(tt2 + 1) * 128], c1v);
    }
    sc[tp * 128 + v] = c0 + c1v;
  }
  __syncthreads();
  if (tid < 128) {
    float s = 0.f;
#pragma unroll
    for (int tp = 0; tp < 8; ++tp) s += sc[tp * 128 + tid];
    gadd(&p.ctxnum[par * 4096 + b * 128 + tid], s);
  }
}

// ---------------- the persistent decode loop ----------------
__global__ void __launch_bounds__(1024, 4) k_loop(P p) {
  __shared__ __align__(16) float smem[5600];
  __shared__ __align__(16) float sfin[640];
  __shared__ int smi[32];
  const int blk = blockIdx.x, tid = threadIdx.x;
  unsigned nb = 0;
  phase_att(p, 0, smem, blk, tid);
  for (int i = 1; i < 64; ++i) {
    gbar(p.bar, blk, ++nb);
    phase_g1(p, i, smem, smi, sfin, blk, tid);
    gbar(p.bar, blk, ++nb);
    phase_g2(p, i, smem, blk, tid);
    gbar(p.bar, blk, ++nb);
    phase_att(p, i, smem, blk, tid);
  }
  gbar(p.bar, blk, ++nb);
  // FIN: atts(63) + finalize(63)
  if (tid < 256) {
    int flat = blk * 256 + tid;
    int b = flat >> 11, t = flat & 2047;
    float s = fmaxf(gload(&p.Ssum[1 * 32 + b]), 1e-12f);   // 63&1 == 1
    p.out[133120 + (size_t)(63 * 32 + b) * 2048 + t] = gload(&p.wbuf[b * 2048 + t]) / s;
  }
  if (blk < 32 && tid < 64) do_finalize(p, 63, blk, tid, sfin);
}

extern "C" void kernel_launch(void* const* d_in, const int* in_sizes, int n_in,
                              void* d_out, int out_size, void* d_ws, size_t ws_size,
                              hipStream_t stream) {
  P p;
  p.listener = (const float*)d_in[0];
  p.outlen   = (const int*)d_in[1];
  p.ptgt     = (const int*)d_in[2];
  // d_in[3] = teacher_forcing (==1: always teacher-forced)
  p.embed = (const float*)d_in[4];
  p.W_ih1 = (const float*)d_in[5];  p.W_hh1 = (const float*)d_in[6];
  p.b_ih1 = (const float*)d_in[7];  p.b_hh1 = (const float*)d_in[8];
  p.W_ih2 = (const float*)d_in[9];  p.W_hh2 = (const float*)d_in[10];
  p.b_ih2 = (const float*)d_in[11]; p.b_hh2 = (const float*)d_in[12];
  p.W_s = (const float*)d_in[13]; p.b_s = (const float*)d_in[14];
  p.W_h = (const float*)d_in[15]; p.b_h = (const float*)d_in[16];
  p.W_v = (const float*)d_in[17]; p.b_v = (const float*)d_in[18];
  p.W_c = (const float*)d_in[19]; p.b_c = (const float*)d_in[20];
  p.h1_0 = (const float*)d_in[21]; p.c1_0 = (const float*)d_in[22];
  p.h2_0 = (const float*)d_in[23]; p.c2_0 = (const float*)d_in[24];

  char* w = (char*)d_ws;
  p.keyT   = (float*)w; w += (size_t)32 * 128 * 2048 * 4;   // 32 MB
  p.value  = (float*)w; w += (size_t)32 * 2048 * 128 * 4;   // 32 MB
  p.h1  = (float*)w; w += 2 * 32 * 512 * 4;
  p.c1  = (float*)w; w += 2 * 32 * 512 * 4;
  p.h2  = (float*)w; w += 2 * 32 * 512 * 4;
  p.c2  = (float*)w; w += 2 * 32 * 512 * 4;
  p.wbuf   = (float*)w; w += 32 * 2048 * 4;
  p.ctxnum = (float*)w; w += 2 * 32 * 128 * 4;
  p.Ssum   = (float*)w; w += 2 * 32 * 4;
  p.bar    = (BarCtr*)w; w += 8 * sizeof(BarCtr);
  p.out = (float*)d_out;

  k_init<<<64, 256, 0, stream>>>(p);
  k_proj<<<4096, 256, 0, stream>>>(p);
  k_loop<<<256, 1024, 0, stream>>>(p);
}

// Round 5
// 6090.406 us; speedup vs baseline: 1.8651x; 1.1069x over previous
//
#include <hip/hip_runtime.h>
#include <stdint.h>
#include <stddef.h>

// Problem dims (fixed): B=32 TENC=2048 LIS=512 HID=512 EMB=256 CLS=64 KEY=128 VAL=128 T=64 steps
// Outputs (f32, concat): logits [64,32,64] @0 ; preds.T [32,64] @131072 ; atts [64,32,2048] @133120
// Structure: k_init + k_proj + ONE persistent kernel (256 blocks x 1024 thr, exactly 1/CU).
// NEW (R5): each block's step-invariant attention slice is pinned ON-CHIP for all 64 steps:
//   keyT slice [128 k][256 t] f32 -> 128 KB static LDS; value slice -> 32 VGPRs/thread (va[32]).
//   => ATT does no global reads in steady state; LSTM weights become L2-resident (no stream evict).
// Cross-block mutable state (h1,h2,ctxnum,Ssum,wbuf,bar) via relaxed AGENT-scope atomics.
// Barrier: syncthreads + relaxed add on 8 spread cachelines + relaxed spin (no cache invalidates).
//   per step i (1..63):  bar; G1 (gates1+act1, +atts(i-1), +finalize(i-1));
//                        bar; G2 (gates2+act2, +zero next-parity accum);
//                        bar; ATT (query, energies, exp, Ssum/ctxnum partials)

struct BarCtr { unsigned v; unsigned pad[31]; };  // 128 B apart

struct P {
  const float* listener; const int* outlen; const int* ptgt;
  const float* embed;
  const float *W_ih1, *W_hh1, *b_ih1, *b_hh1;
  const float *W_ih2, *W_hh2, *b_ih2, *b_hh2;
  const float *W_s, *b_s, *W_h, *b_h, *W_v, *b_v, *W_c, *b_c;
  const float *h1_0, *c1_0, *h2_0, *c2_0;
  float* keyT;            // [32][128][2048]
  float* value;           // [32][2048][128]
  float* h1;              // [2][32][512] ping-pong by step parity (cross-block -> atomics)
  float* c1;              // [2][32][512] block-private (plain)
  float* h2;              // [2][32][512] cross-block -> atomics
  float* c2;              // [2][32][512] block-private (plain)
  float* wbuf;            // [32][2048]  cross-block -> atomics
  float* ctxnum;          // [2][32][128] cross-block -> atomics
  float* Ssum;            // [2][32]      cross-block -> atomics
  BarCtr* bar;            // 8 counters
  float* out;
};

__device__ __forceinline__ float sigf(float x) { return 1.0f / (1.0f + expf(-x)); }

__device__ __forceinline__ float gload(const float* p) {
  return __hip_atomic_load(p, __ATOMIC_RELAXED, __HIP_MEMORY_SCOPE_AGENT);
}
__device__ __forceinline__ void gstore(float* p, float v) {
  __hip_atomic_store(p, v, __ATOMIC_RELAXED, __HIP_MEMORY_SCOPE_AGENT);
}
__device__ __forceinline__ void gadd(float* p, float v) {
  __hip_atomic_fetch_add(p, v, __ATOMIC_RELAXED, __HIP_MEMORY_SCOPE_AGENT);
}

// exact jax threefry2x32 (20 rounds)
__device__ __forceinline__ void tf2x32(uint32_t k0, uint32_t k1,
                                       uint32_t x0, uint32_t x1,
                                       uint32_t& o0, uint32_t& o1) {
  uint32_t k2 = k0 ^ k1 ^ 0x1BD11BDAu;
#define TFR(r) { x0 += x1; x1 = (x1 << (r)) | (x1 >> (32 - (r))); x1 ^= x0; }
  x0 += k0; x1 += k1;
  TFR(13) TFR(15) TFR(26) TFR(6)   x0 += k1; x1 += k2 + 1u;
  TFR(17) TFR(29) TFR(16) TFR(24)  x0 += k2; x1 += k0 + 2u;
  TFR(13) TFR(15) TFR(26) TFR(6)   x0 += k0; x1 += k1 + 3u;
  TFR(17) TFR(29) TFR(16) TFR(24)  x0 += k1; x1 += k2 + 4u;
  TFR(13) TFR(15) TFR(26) TFR(6)   x0 += k2; x1 += k0 + 5u;
#undef TFR
  o0 = x0; o1 = x1;
}

__device__ __forceinline__ float gumbel_f(uint32_t bits) {
  float f = __uint_as_float((bits >> 9) | 0x3f800000u) - 1.0f;
  float u = (f == 0.0f) ? 1.17549435e-38f : f;
  return -logf(-logf(u));
}

// ---- software grid barrier: NO cache maintenance (shared data goes via agent atomics) ----
__device__ __forceinline__ void gbar(BarCtr* bar, int blk, unsigned round) {
  __syncthreads();
  if (threadIdx.x == 0) {
    __hip_atomic_fetch_add(&bar[blk & 7].v, 1u, __ATOMIC_RELAXED, __HIP_MEMORY_SCOPE_AGENT);
    const unsigned tgt = round * 256u;
    for (;;) {
      unsigned s = 0;
#pragma unroll
      for (int c = 0; c < 8; ++c)
        s += __hip_atomic_load(&bar[c].v, __ATOMIC_RELAXED, __HIP_MEMORY_SCOPE_AGENT);
      if (s >= tgt) break;
      __builtin_amdgcn_s_sleep(1);
    }
    asm volatile("" ::: "memory");
  }
  __syncthreads();
}

// ---------------- init: states (parity 0) + zero accumulators + barrier counters ----------------
__global__ void __launch_bounds__(256) k_init(P p) {
  int idx = blockIdx.x * 256 + threadIdx.x;   // grid 64*256 = 16384
  p.h1[idx] = p.h1_0[idx];
  p.c1[idx] = p.c1_0[idx];
  p.h2[idx] = p.h2_0[idx];
  p.c2[idx] = p.c2_0[idx];
  if (idx < 8192) p.ctxnum[idx] = 0.0f;
  if (idx < 64)   p.Ssum[idx]   = 0.0f;
  if (idx < 8)    p.bar[idx].v  = 0u;
}

// ---------------- hoisted projections: key_enc (f32, transposed) + value (f32) ----------------
__global__ void __launch_bounds__(256) k_proj(P p) {
  const int blk = blockIdx.x, tid = threadIdx.x;      // grid 4096
  const int b = blk >> 7, tb = blk & 127, t0 = tb * 16;
  __shared__ float lst[16 * 512];                     // 32 KB
  const float* src = p.listener + ((size_t)b * 2048 + t0) * 512;
  for (int n = 0; n < 32; ++n) {
    int idx = n * 256 + tid;
    lst[idx] = src[idx];
  }
  __syncthreads();
  const int c = tid;
  const float* wr = (c < 128) ? (p.W_h + c * 512) : (p.W_v + (c - 128) * 512);
  const float bias = (c < 128) ? p.b_h[c] : p.b_v[c - 128];
  float acc[16];
#pragma unroll
  for (int r = 0; r < 16; ++r) acc[r] = 0.0f;
  for (int k4 = 0; k4 < 128; ++k4) {
    float4 w4 = ((const float4*)wr)[k4];
#pragma unroll
    for (int r = 0; r < 16; ++r) {
      float4 x4 = ((const float4*)(lst + r * 512))[k4];
      acc[r] = fmaf(w4.x, x4.x, fmaf(w4.y, x4.y, fmaf(w4.z, x4.z, fmaf(w4.w, x4.w, acc[r]))));
    }
  }
  if (c < 128) {
#pragma unroll
    for (int r = 0; r < 16; ++r)
      p.keyT[((size_t)b * 128 + c) * 2048 + t0 + r] = acc[r] + bias;
  } else {
#pragma unroll
    for (int r = 0; r < 16; ++r)
      p.value[((size_t)b * 2048 + t0 + r) * 128 + (c - 128)] = acc[r] + bias;
  }
}

// ---------------- finalize step `step` for batch b: logits + categorical sample ----------------
// executed by one full wave (tid = 0..63); sf = 640-float LDS scratch (aliases dead sx region)
__device__ void do_finalize(const P& p, int step, int b, int tid, float* sf) {
  const int c = tid;
  const int par = step & 1;
  const float* h2p  = p.h2 + par * 16384 + b * 512;
  const float* ctxp = p.ctxnum + par * 4096 + b * 128;
  const float invS = 1.0f / fmaxf(gload(&p.Ssum[par * 32 + b]), 1e-12f);
#pragma unroll
  for (int n = 0; n < 10; ++n) {
    int idx = n * 64 + c;
    float v = (idx < 512) ? gload(&h2p[idx]) : gload(&ctxp[idx - 512]) * invS;
    sf[idx] = v;
  }
  asm volatile("s_waitcnt vmcnt(0) lgkmcnt(0)" ::: "memory");
  __builtin_amdgcn_wave_barrier();
  const float* wr = p.W_c + c * 640;
  float a0 = 0.f, a1 = 0.f, a2 = 0.f, a3 = 0.f;
#pragma unroll 8
  for (int k4 = 0; k4 < 160; ++k4) {
    float4 w4 = ((const float4*)wr)[k4];
    float4 x4 = ((const float4*)sf)[k4];
    a0 = fmaf(w4.x, x4.x, a0); a1 = fmaf(w4.y, x4.y, a1);
    a2 = fmaf(w4.z, x4.z, a2); a3 = fmaf(w4.w, x4.w, a3);
  }
  float lg = p.b_c[c] + ((a0 + a1) + (a2 + a3));
  p.out[(size_t)(step * 32 + b) * 64 + c] = lg;
  uint32_t n0, n1, r0, r1;
  tf2x32(0u, 2u, 0u, (uint32_t)step, n0, n1);          // fold_in(key(2), step)
  tf2x32(n0, n1, 0u, (uint32_t)(b * 64 + c), r0, r1);  // partitionable bits at pos b*64+c
  float z = gumbel_f(r0 ^ r1) + lg;
  int ix = c;
  for (int off = 32; off; off >>= 1) {
    float zz = __shfl_xor(z, off, 64); int ii = __shfl_xor(ix, off, 64);
    if (zz > z || (zz == z && ii < ix)) { z = zz; ix = ii; }
  }
  if (c == 0) p.out[131072 + b * 64 + step] = (float)ix;
}

// ---------------- phase G1 (1024 thr): gates1 + act1; + atts(i-1) + finalize(i-1) ----------------
__device__ void phase_g1(const P& p, int i, float* smem, int* smi, int blk, int tid) {
  const int par = i & 1, q1 = par ^ 1;
  float* sx   = smem;          // 32*132 = 4224
  float* sp   = smem + 4224;   // 1024 partials
  float* sg   = smem + 5248;   // 256 gates
  float* sinv = smem + 5504;   // 32
  if (tid < 256) {   // atts output for step i-1
    int flat = blk * 256 + tid;
    int b = flat >> 11, t = flat & 2047;
    float s = fmaxf(gload(&p.Ssum[q1 * 32 + b]), 1e-12f);
    p.out[133120 + (size_t)((i - 1) * 32 + b) * 2048 + t] = gload(&p.wbuf[b * 2048 + t]) / s;
  }
  if (tid < 32) {
    sinv[tid] = 1.0f / fmaxf(gload(&p.Ssum[q1 * 32 + tid]), 1e-12f);
    smi[tid]  = p.ptgt[tid * 65 + (i - 1)];   // teacher forcing == 1 always
  }
  const int b = tid & 31, m = (tid >> 5) & 7, q = tid >> 8;
  const int j0 = blk * 2;
  const int row = j0 + (m & 1) + (m >> 1) * 512;
  const float* h1r  = p.h1 + q1 * 16384;
  const float* ctxr = p.ctxnum + q1 * 4096;
  float a0 = 0.f, a1 = 0.f, a2 = 0.f, a3 = 0.f;
  for (int kt = 0; kt < 7; ++kt) {   // K = 896 = 2*128 emb + 128 ctx + 4*128 h1
    __syncthreads();
#pragma unroll
    for (int n = 0; n < 4; ++n) {
      int idx = n * 1024 + tid, fb = idx >> 7, kk = idx & 127;
      float v;
      if (kt < 2)       v = p.embed[smi[fb] * 256 + kt * 128 + kk];
      else if (kt == 2) v = gload(&ctxr[fb * 128 + kk]) * sinv[fb];
      else              v = gload(&h1r[fb * 512 + (kt - 3) * 128 + kk]);
      sx[fb * 132 + kk] = v;
    }
    __syncthreads();
    const float* wr = (kt < 3) ? (p.W_ih1 + row * 384 + kt * 128)
                               : (p.W_hh1 + row * 512 + (kt - 3) * 128);
    const float4* w4p = (const float4*)(wr + q * 32);
    const float4* x4p = (const float4*)(sx + b * 132 + q * 32);
#pragma unroll
    for (int k4 = 0; k4 < 8; ++k4) {
      float4 w4 = w4p[k4], x4 = x4p[k4];
      a0 = fmaf(w4.x, x4.x, a0); a1 = fmaf(w4.y, x4.y, a1);
      a2 = fmaf(w4.z, x4.z, a2); a3 = fmaf(w4.w, x4.w, a3);
    }
  }
  sp[q * 256 + m * 32 + b] = (a0 + a1) + (a2 + a3);
  __syncthreads();
  if (tid < 256) {
    int mm = tid >> 5;
    int rr = j0 + (mm & 1) + (mm >> 1) * 512;
    sg[tid] = sp[tid] + sp[256 + tid] + sp[512 + tid] + sp[768 + tid]
            + p.b_ih1[rr] + p.b_hh1[rr];
  }
  __syncthreads();
  if (tid < 64) {
    int jl = tid >> 5, bb = tid & 31, j = j0 + jl;
    float gi = sg[(0 + jl) * 32 + bb];
    float gf = sg[(2 + jl) * 32 + bb];
    float gg = sg[(4 + jl) * 32 + bb];
    float go = sg[(6 + jl) * 32 + bb];
    float cp = p.c1[q1 * 16384 + bb * 512 + j];           // block-private: plain
    float c  = sigf(gf) * cp + sigf(gi) * tanhf(gg);
    gstore(&p.h1[par * 16384 + bb * 512 + j], sigf(go) * tanhf(c));
    p.c1[par * 16384 + bb * 512 + j] = c;                 // block-private: plain
  }
  if (blk < 32 && tid < 64) do_finalize(p, i - 1, blk, tid, smem);  // sx region dead here
}

// ---------------- phase G2 (1024 thr): gates2 + act2; + zero next-parity accumulators ----------------
__device__ void phase_g2(const P& p, int i, float* smem, int blk, int tid) {
  const int par = i & 1, q1 = par ^ 1;
  float* sx = smem;
  float* sp = smem + 4224;
  float* sg = smem + 5248;
  if (blk < 4) gstore(&p.ctxnum[q1 * 4096 + blk * 1024 + tid], 0.0f);
  if (blk == 4 && tid < 32) gstore(&p.Ssum[q1 * 32 + tid], 0.0f);
  const int b = tid & 31, m = (tid >> 5) & 7, q = tid >> 8;
  const int j0 = blk * 2;
  const int row = j0 + (m & 1) + (m >> 1) * 512;
  const float* h1r = p.h1 + par * 16384;
  const float* h2r = p.h2 + q1 * 16384;
  float a0 = 0.f, a1 = 0.f, a2 = 0.f, a3 = 0.f;
  for (int kt = 0; kt < 8; ++kt) {  // K = 1024 = 4*128 h1 + 4*128 h2prev
    __syncthreads();
#pragma unroll
    for (int n = 0; n < 4; ++n) {
      int idx = n * 1024 + tid, fb = idx >> 7, kk = idx & 127;
      float v = (kt < 4) ? gload(&h1r[fb * 512 + kt * 128 + kk])
                         : gload(&h2r[fb * 512 + (kt - 4) * 128 + kk]);
      sx[fb * 132 + kk] = v;
    }
    __syncthreads();
    const float* wr = (kt < 4) ? (p.W_ih2 + row * 512 + kt * 128)
                               : (p.W_hh2 + row * 512 + (kt - 4) * 128);
    const float4* w4p = (const float4*)(wr + q * 32);
    const float4* x4p = (const float4*)(sx + b * 132 + q * 32);
#pragma unroll
    for (int k4 = 0; k4 < 8; ++k4) {
      float4 w4 = w4p[k4], x4 = x4p[k4];
      a0 = fmaf(w4.x, x4.x, a0); a1 = fmaf(w4.y, x4.y, a1);
      a2 = fmaf(w4.z, x4.z, a2); a3 = fmaf(w4.w, x4.w, a3);
    }
  }
  sp[q * 256 + m * 32 + b] = (a0 + a1) + (a2 + a3);
  __syncthreads();
  if (tid < 256) {
    int mm = tid >> 5;
    int rr = j0 + (mm & 1) + (mm >> 1) * 512;
    sg[tid] = sp[tid] + sp[256 + tid] + sp[512 + tid] + sp[768 + tid]
            + p.b_ih2[rr] + p.b_hh2[rr];
  }
  __syncthreads();
  if (tid < 64) {
    int jl = tid >> 5, bb = tid & 31, j = j0 + jl;
    float gi = sg[(0 + jl) * 32 + bb];
    float gf = sg[(2 + jl) * 32 + bb];
    float gg = sg[(4 + jl) * 32 + bb];
    float go = sg[(6 + jl) * 32 + bb];
    float cp = p.c2[q1 * 16384 + bb * 512 + j];           // block-private: plain
    float c  = sigf(gf) * cp + sigf(gi) * tanhf(gg);
    gstore(&p.h2[par * 16384 + bb * 512 + j], sigf(go) * tanhf(c));
    p.c2[par * 16384 + bb * 512 + j] = c;                 // block-private: plain
  }
}

// ---------------- phase ATT (1024 thr): query, energies (keys in LDS), ctx (value in regs) ----------------
// 256 blocks = 32 b x 8 chunks of 256 t ; kslice[k][tt] = keyT[b][k][t0+tt] ; va = value regs
__device__ __forceinline__ void phase_att(const P& p, int i, float* smem, const float* kslice,
                                          const float va[32], int blk, int tid) {
  const int par = i & 1;
  const int b = blk >> 3;
  float* sh2 = smem;          // 512
  float* sq  = smem + 512;    // 128
  float* sqp = smem + 640;    // 512
  float* se  = smem + 1152;   // 1024
  float* sw  = smem + 2176;   // 256
  float* swr = smem + 2432;   // 8
  float* sc  = smem + 2440;   // 1024
  const float* h2p = p.h2 + par * 16384 + b * 512;
  if (tid < 512) sh2[tid] = gload(&h2p[tid]);
  __syncthreads();
  if (tid < 512) {  // query partials: (col, K-quarter)
    int col = tid & 127, qh = tid >> 7;
    const float* wr = p.W_s + col * 512 + qh * 128;
    const float4* h4p = (const float4*)(sh2 + qh * 128);
    float a0 = 0.f, a1 = 0.f, a2 = 0.f, a3 = 0.f;
#pragma unroll
    for (int j4 = 0; j4 < 32; ++j4) {
      float4 w4 = ((const float4*)wr)[j4], h4 = h4p[j4];
      a0 = fmaf(w4.x, h4.x, a0); a1 = fmaf(w4.y, h4.y, a1);
      a2 = fmaf(w4.z, h4.z, a2); a3 = fmaf(w4.w, h4.w, a3);
    }
    sqp[qh * 128 + col] = (a0 + a1) + (a2 + a3);
  }
  __syncthreads();
  if (tid < 128) sq[tid] = p.b_s[tid] + sqp[tid] + sqp[128 + tid] + sqp[256 + tid] + sqp[384 + tid];
  __syncthreads();
  {  // energy partials from LDS keys: (t, K-quarter of 32)
    int tt = tid & 255, kq = tid >> 8;
    const float* kc = kslice + tt;
    const int kb = kq * 32;
    float e0 = 0.f, e1 = 0.f, e2 = 0.f, e3 = 0.f;
#pragma unroll 8
    for (int k = 0; k < 32; k += 4) {
      e0 = fmaf(kc[(kb + k + 0) * 256], sq[kb + k + 0], e0);
      e1 = fmaf(kc[(kb + k + 1) * 256], sq[kb + k + 1], e1);
      e2 = fmaf(kc[(kb + k + 2) * 256], sq[kb + k + 2], e2);
      e3 = fmaf(kc[(kb + k + 3) * 256], sq[kb + k + 3], e3);
    }
    se[kq * 256 + tt] = (e0 + e1) + (e2 + e3);
  }
  __syncthreads();
  if (tid < 256) {
    const int ch = blk & 7, t0 = ch * 256;
    int t = t0 + tid;
    float e = se[tid] + se[256 + tid] + se[512 + tid] + se[768 + tid];
    const int len = p.outlen[b];
    bool msk = (b == 0) || (t < len);
    float wv = msk ? expf(e) : 0.0f;
    gstore(&p.wbuf[b * 2048 + t], wv);
    sw[tid] = wv;
    float s = wv;
    for (int off = 32; off; off >>= 1) s += __shfl_xor(s, off, 64);
    if ((tid & 63) == 0) swr[tid >> 6] = s;
  }
  __syncthreads();
  if (tid == 0) gadd(&p.Ssum[par * 32 + b], swr[0] + swr[1] + swr[2] + swr[3]);
  {  // ctx partials from register-resident value: (v, t-octant of 32)
    int v = tid & 127, tp = tid >> 7;
    float c0 = 0.f, c1v = 0.f;
#pragma unroll
    for (int tt2 = 0; tt2 < 32; tt2 += 2) {
      c0  = fmaf(sw[tp * 32 + tt2],     va[tt2],     c0);
      c1v = fmaf(sw[tp * 32 + tt2 + 1], va[tt2 + 1], c1v);
    }
    sc[tp * 128 + v] = c0 + c1v;
  }
  __syncthreads();
  if (tid < 128) {
    float s = 0.f;
#pragma unroll
    for (int tp = 0; tp < 8; ++tp) s += sc[tp * 128 + tid];
    gadd(&p.ctxnum[par * 4096 + b * 128 + tid], s);
  }
}

// ---------------- the persistent decode loop ----------------
__global__ void __launch_bounds__(1024, 4) k_loop(P p) {
  __shared__ __align__(16) float kslice[128 * 256];   // 128 KB: this block's keyT slice
  __shared__ __align__(16) float smem[5600];          // 22.4 KB working
  __shared__ int smi[32];
  const int blk = blockIdx.x, tid = threadIdx.x;
  const int b_att = blk >> 3, ch = blk & 7, t0 = ch * 256;
  // ---- one-time on-chip pinning of the step-invariant attention slice ----
  {
    const float* ksrc = p.keyT + (size_t)b_att * 262144 + t0;
    for (int n = 0; n < 32; ++n) {
      int idx = n * 1024 + tid;          // 0..32767
      int k = idx >> 8, tt = idx & 255;
      kslice[k * 256 + tt] = ksrc[(size_t)k * 2048 + tt];
    }
  }
  float va[32];
  {
    int v = tid & 127, tp = tid >> 7;
    const float* vb = p.value + ((size_t)(b_att * 2048 + t0 + tp * 32)) * 128 + v;
#pragma unroll
    for (int tt2 = 0; tt2 < 32; ++tt2) va[tt2] = vb[(size_t)tt2 * 128];
  }
  __syncthreads();
  unsigned nb = 0;
  phase_att(p, 0, smem, kslice, va, blk, tid);
  for (int i = 1; i < 64; ++i) {
    gbar(p.bar, blk, ++nb);
    phase_g1(p, i, smem, smi, blk, tid);
    gbar(p.bar, blk, ++nb);
    phase_g2(p, i, smem, blk, tid);
    gbar(p.bar, blk, ++nb);
    phase_att(p, i, smem, kslice, va, blk, tid);
  }
  gbar(p.bar, blk, ++nb);
  // FIN: atts(63) + finalize(63)
  if (tid < 256) {
    int flat = blk * 256 + tid;
    int b = flat >> 11, t = flat & 2047;
    float s = fmaxf(gload(&p.Ssum[1 * 32 + b]), 1e-12f);   // 63&1 == 1
    p.out[133120 + (size_t)(63 * 32 + b) * 2048 + t] = gload(&p.wbuf[b * 2048 + t]) / s;
  }
  if (blk < 32 && tid < 64) do_finalize(p, 63, blk, tid, smem);
}

extern "C" void kernel_launch(void* const* d_in, const int* in_sizes, int n_in,
                              void* d_out, int out_size, void* d_ws, size_t ws_size,
                              hipStream_t stream) {
  P p;
  p.listener = (const float*)d_in[0];
  p.outlen   = (const int*)d_in[1];
  p.ptgt     = (const int*)d_in[2];
  // d_in[3] = teacher_forcing (==1: always teacher-forced)
  p.embed = (const float*)d_in[4];
  p.W_ih1 = (const float*)d_in[5];  p.W_hh1 = (const float*)d_in[6];
  p.b_ih1 = (const float*)d_in[7];  p.b_hh1 = (const float*)d_in[8];
  p.W_ih2 = (const float*)d_in[9];  p.W_hh2 = (const float*)d_in[10];
  p.b_ih2 = (const float*)d_in[11]; p.b_hh2 = (const float*)d_in[12];
  p.W_s = (const float*)d_in[13]; p.b_s = (const float*)d_in[14];
  p.W_h = (const float*)d_in[15]; p.b_h = (const float*)d_in[16];
  p.W_v = (const float*)d_in[17]; p.b_v = (const float*)d_in[18];
  p.W_c = (const float*)d_in[19]; p.b_c = (const float*)d_in[20];
  p.h1_0 = (const float*)d_in[21]; p.c1_0 = (const float*)d_in[22];
  p.h2_0 = (const float*)d_in[23]; p.c2_0 = (const float*)d_in[24];

  char* w = (char*)d_ws;
  p.keyT   = (float*)w; w += (size_t)32 * 128 * 2048 * 4;   // 32 MB
  p.value  = (float*)w; w += (size_t)32 * 2048 * 128 * 4;   // 32 MB
  p.h1  = (float*)w; w += 2 * 32 * 512 * 4;
  p.c1  = (float*)w; w += 2 * 32 * 512 * 4;
  p.h2  = (float*)w; w += 2 * 32 * 512 * 4;
  p.c2  = (float*)w; w += 2 * 32 * 512 * 4;
  p.wbuf   = (float*)w; w += 32 * 2048 * 4;
  p.ctxnum = (float*)w; w += 2 * 32 * 128 * 4;
  p.Ssum   = (float*)w; w += 2 * 32 * 4;
  p.bar    = (BarCtr*)w; w += 8 * sizeof(BarCtr);
  p.out = (float*)d_out;

  k_init<<<64, 256, 0, stream>>>(p);
  k_proj<<<4096, 256, 0, stream>>>(p);
  k_loop<<<256, 1024, 0, stream>>>(p);
}